// Round 12
// baseline (97.066 us; speedup 1.0000x reference)
//
#include <hip/hip_runtime.h>
#include <hip/hip_bf16.h>

#define N 8192
#define D 512
#define BT 128
#define BK 64
#define NCB (N / BT)   // 64 column blocks
#define NKT (D / BK)   // 8 K tiles
#define NTRI (NCB * (NCB + 1) / 2)  // 2080 upper-triangle blocks (2080 % 8 == 0)
#define INVT 14.285714285714286f

typedef __attribute__((ext_vector_type(8))) short bf16x8;
typedef __attribute__((ext_vector_type(4))) float f32x4;
typedef __attribute__((ext_vector_type(8))) unsigned short u16x8;

__device__ __forceinline__ unsigned short f2bf(float f) {
  __hip_bfloat16 h = __float2bfloat16(f);
  return *reinterpret_cast<unsigned short*>(&h);
}

// ---------------- kernel 1: L2-normalize rows -> bf16; zero out[0] ----------
__global__ __launch_bounds__(256) void k_normalize(const float* __restrict__ x,
                                                   unsigned short* __restrict__ fb,
                                                   float* __restrict__ out) {
  const int row = blockIdx.x * 4 + (threadIdx.x >> 6);
  const int lane = threadIdx.x & 63;
  const float* rp = x + (size_t)row * D + lane * 8;
  float4 v0 = *reinterpret_cast<const float4*>(rp);
  float4 v1 = *reinterpret_cast<const float4*>(rp + 4);
  float s = v0.x*v0.x + v0.y*v0.y + v0.z*v0.z + v0.w*v0.w
          + v1.x*v1.x + v1.y*v1.y + v1.z*v1.z + v1.w*v1.w;
  #pragma unroll
  for (int m = 1; m < 64; m <<= 1) s += __shfl_xor(s, m);
  float inv = 1.0f / fmaxf(sqrtf(s), 1e-12f);
  u16x8 o;
  o[0] = f2bf(v0.x*inv); o[1] = f2bf(v0.y*inv); o[2] = f2bf(v0.z*inv); o[3] = f2bf(v0.w*inv);
  o[4] = f2bf(v1.x*inv); o[5] = f2bf(v1.y*inv); o[6] = f2bf(v1.z*inv); o[7] = f2bf(v1.w*inv);
  *reinterpret_cast<u16x8*>(fb + (size_t)row * D + lane * 8) = o;
  if (blockIdx.x == 0 && threadIdx.x == 0) out[0] = 0.0f;
}

// ---------------- kernel 2: fused GEMM + exp-rowsum + masked-sum -------------
// R12 design: same 128x128 tile, but 8 waves x (64x32 wave-tile) -> acc[4][2]
// = 32 AGPR. Per-wave unified budget <=128 -> 16 waves/CU = 4 waves/SIMD (vs
// R7's 3), the max TLP for a GEMM holding a >=32-reg accumulator. Dbuf is
// LDS-free at this occupancy (71KB x 2 = 142 <= 160). Combines R8's per-slot-
// better dbuf (138 vs 171 block-us) with MORE occupancy than R7.
// Staging, swizzle, triangle decode, epilogue: validated R7 forms.
#define GLOAD_LDS16(g, l) __builtin_amdgcn_global_load_lds( \
    (const __attribute__((address_space(1))) unsigned int*)(g), \
    (__attribute__((address_space(3))) unsigned int*)(l), 16, 0, 0)

__global__ __launch_bounds__(512, 4) void k_gemm(
    const unsigned short* __restrict__ fb, const int* __restrict__ labels,
    float* __restrict__ part_e, float* __restrict__ part_p) {
  __shared__ __align__(16) short As0[BT * BK];   // 16 KB each
  __shared__ __align__(16) short As1[BT * BK];
  __shared__ __align__(16) short Bs0[BT * BK];
  __shared__ __align__(16) short Bs1[BT * BK];
  __shared__ float e_part[4][BT];   // row-partials, indexed by wc (4 col-groups)
  __shared__ float p_part[4][BT];
  __shared__ float e_cpart[2][BT];  // col-partials, indexed by wr (2 row-groups)
  __shared__ float p_cpart[2][BT];
  __shared__ int labR[BT];
  __shared__ int labC[BT];

  const int tid = threadIdx.x;
  const int lane = tid & 63;
  const int w = tid >> 6;           // 0..7
  const int wr = w >> 2;            // 0..1 : 64-row group
  const int wc = w & 3;             // 0..3 : 32-col group
  const int l15 = lane & 15;

  // XCD-chunked bijective swizzle (NTRI % 8 == 0)
  const int b0 = blockIdx.x;
  const int t = (b0 & 7) * (NTRI / 8) + (b0 >> 3);

  // triangle index -> (bx, by), by <= bx
  int bx = (int)((sqrtf(8.0f * (float)t + 1.0f) - 1.0f) * 0.5f);
  while ((bx + 1) * (bx + 2) / 2 <= t) ++bx;
  while (bx * (bx + 1) / 2 > t) --bx;
  const int by = t - bx * (bx + 1) / 2;
  const bool offdiag = (bx != by);

  const int rowA0 = by * BT, rowB0 = bx * BT;

  if (tid < BT) labR[tid] = labels[rowA0 + tid];
  else if (tid < 2 * BT) labC[tid - BT] = labels[rowB0 + (tid - BT)];

  f32x4 acc[4][2] = {};
  const int sslot = tid & 7;

  // 512 threads stage a 16KB panel in 2 iterations of 16B each.
#define STAGE_TILE(kt, AD, BD) do { \
    const int kbase_ = (kt) * BK; \
    _Pragma("unroll") \
    for (int it = 0; it < 2; ++it) { \
      int r = (it * 512 + tid) >> 3; \
      int kcol = ((sslot ^ (r & 7)) << 3) + kbase_; \
      GLOAD_LDS16(fb + (size_t)(rowA0 + r) * D + kcol, \
                  (char*)(AD) + it * 8192 + tid * 16); \
    } \
    _Pragma("unroll") \
    for (int it = 0; it < 2; ++it) { \
      int r = (it * 512 + tid) >> 3; \
      int kcol = ((sslot ^ (r & 7)) << 3) + kbase_; \
      GLOAD_LDS16(fb + (size_t)(rowB0 + r) * D + kcol, \
                  (char*)(BD) + it * 8192 + tid * 16); \
    } } while (0)

#define COMPUTE_TILE(AS, BS) do { \
    _Pragma("unroll") \
    for (int kk = 0; kk < BK; kk += 32) { \
      bf16x8 af[4], bg[2]; \
      int kb = (kk + ((lane >> 4) << 3)) * 2; \
      _Pragma("unroll") \
      for (int m = 0; m < 4; ++m) { \
        int ar = wr * 64 + m * 16 + l15; \
        af[m] = *reinterpret_cast<const bf16x8*>( \
            (const char*)(AS) + ar * 128 + (kb ^ ((ar & 7) << 4))); \
      } \
      _Pragma("unroll") \
      for (int n = 0; n < 2; ++n) { \
        int br = wc * 32 + n * 16 + l15; \
        bg[n] = *reinterpret_cast<const bf16x8*>( \
            (const char*)(BS) + br * 128 + (kb ^ ((br & 7) << 4))); \
      } \
      _Pragma("unroll") \
      for (int m = 0; m < 4; ++m) \
        _Pragma("unroll") \
        for (int n = 0; n < 2; ++n) \
          acc[m][n] = __builtin_amdgcn_mfma_f32_16x16x32_bf16(af[m], bg[n], acc[m][n], 0, 0, 0); \
    } } while (0)

  // prologue: tile 0 -> buf0
  STAGE_TILE(0, As0, Bs0);
  __syncthreads();

  #pragma unroll
  for (int kt = 0; kt < NKT; ++kt) {
    if ((kt & 1) == 0) {
      if (kt + 1 < NKT) STAGE_TILE(kt + 1, As1, Bs1);
      COMPUTE_TILE(As0, Bs0);
    } else {
      if (kt + 1 < NKT) STAGE_TILE(kt + 1, As0, Bs0);
      COMPUTE_TILE(As1, Bs1);
    }
    __syncthreads();   // drain: next tile resident (stage had compute-time to land)
  }

  // ---- fused epilogue ----
  float ecol[2] = {};
  float pcol[2] = {};
  int lc[2];
  #pragma unroll
  for (int n = 0; n < 2; ++n)
    lc[n] = labC[wc * 32 + n * 16 + l15];

  #pragma unroll
  for (int m = 0; m < 4; ++m)
    #pragma unroll
    for (int r = 0; r < 4; ++r) {
      int rowl = wr * 64 + m * 16 + ((lane >> 4) << 2) + r;
      int lrv = labR[rowl];
      float e = 0.0f, p = 0.0f;
      #pragma unroll
      for (int n = 0; n < 2; ++n) {
        float s = acc[m][n][r] * INVT;
        float ex = __expf(s);
        float pm = (lrv == lc[n]) ? s : 0.0f;
        e += ex; p += pm;
        ecol[n] += ex; pcol[n] += pm;
      }
      #pragma unroll
      for (int msk = 1; msk < 16; msk <<= 1) {
        e += __shfl_xor(e, msk);
        p += __shfl_xor(p, msk);
      }
      if (l15 == 0) {
        e_part[wc][rowl] = e;
        p_part[wc][rowl] = p;
      }
    }

  // col-partials: reduce across the 4 row-groups (lane>>4)
  if (offdiag) {
    #pragma unroll
    for (int n = 0; n < 2; ++n) {
      float e = ecol[n], p = pcol[n];
      e += __shfl_xor(e, 16); e += __shfl_xor(e, 32);
      p += __shfl_xor(p, 16); p += __shfl_xor(p, 32);
      if (lane < 16) {
        int c = wc * 32 + n * 16 + l15;
        e_cpart[wr][c] = e;
        p_cpart[wr][c] = p;
      }
    }
  }
  __syncthreads();

  if (tid < BT) {
    float e = e_part[0][tid] + e_part[1][tid] + e_part[2][tid] + e_part[3][tid];
    float p = p_part[0][tid] + p_part[1][tid] + p_part[2][tid] + p_part[3][tid];
    size_t off = (size_t)bx * N + rowA0 + tid;
    part_e[off] = e;
    part_p[off] = p;
  } else if (tid < 2 * BT && offdiag) {
    int c = tid - BT;
    float e = e_cpart[0][c] + e_cpart[1][c];
    float p = p_cpart[0][c] + p_cpart[1][c];
    size_t off = (size_t)by * N + rowB0 + c;
    part_e[off] = e;
    part_p[off] = p;
  }
}

// ---------------- kernel 3: per-row loss + atomic mean ----------------------
__global__ __launch_bounds__(256) void k_final(
    const float* __restrict__ part_e, const float* __restrict__ part_p,
    const int* __restrict__ labels, float* __restrict__ out) {
  __shared__ int h[128];
  const int tid = threadIdx.x;
  if (tid < 128) h[tid] = 0;
  __syncthreads();
  for (int j = tid; j < N; j += 256) atomicAdd(&h[labels[j]], 1);

  const int i = blockIdx.x * 256 + tid;
  float e = 0.0f, p = 0.0f;
  #pragma unroll 8
  for (int cb = 0; cb < NCB; ++cb) {
    e += part_e[(size_t)cb * N + i];
    p += part_p[(size_t)cb * N + i];
  }
  __syncthreads();
  float cnt = (float)h[labels[i]];
  float li = logf(e) - p / cnt;
  #pragma unroll
  for (int m = 1; m < 64; m <<= 1) li += __shfl_xor(li, m);
  __shared__ float red[4];
  if ((tid & 63) == 0) red[tid >> 6] = li;
  __syncthreads();
  if (tid == 0)
    atomicAdd(out, (red[0] + red[1] + red[2] + red[3]) * (1.0f / (float)N));
}

extern "C" void kernel_launch(void* const* d_in, const int* in_sizes, int n_in,
                              void* d_out, int out_size, void* d_ws, size_t ws_size,
                              hipStream_t stream) {
  const float* x = (const float*)d_in[0];
  const int* labels = (const int*)d_in[1];
  float* out = (float*)d_out;
  char* ws = (char*)d_ws;

  unsigned short* fb = (unsigned short*)ws;                      // 8 MB bf16 normalized
  float* part_e = (float*)(ws + (size_t)8  * 1024 * 1024);       // 2 MB (64 x 8192)
  float* part_p = (float*)(ws + (size_t)10 * 1024 * 1024);       // 2 MB

  k_normalize<<<N / 4, 256, 0, stream>>>(x, fb, out);
  k_gemm<<<NTRI, 512, 0, stream>>>(fb, labels, part_e, part_p);
  k_final<<<N / 256, 256, 0, stream>>>(part_e, part_p, labels, out);
}

// Round 13
// 81.004 us; speedup vs baseline: 1.1983x; 1.1983x over previous
//
#include <hip/hip_runtime.h>
#include <hip/hip_bf16.h>

#define N 8192
#define D 512
#define BM 128
#define BN 128
#define BK 64
#define NCB (N / BN)   // 64 column blocks
#define NKT (D / BK)   // 8 K tiles
#define NTRI (NCB * (NCB + 1) / 2)  // 2080 upper-triangle blocks (2080 % 8 == 0)
#define INVT 14.285714285714286f

typedef __attribute__((ext_vector_type(8))) short bf16x8;
typedef __attribute__((ext_vector_type(4))) float f32x4;
typedef __attribute__((ext_vector_type(8))) unsigned short u16x8;

__device__ __forceinline__ unsigned short f2bf(float f) {
  __hip_bfloat16 h = __float2bfloat16(f);
  return *reinterpret_cast<unsigned short*>(&h);
}

// ---------------- kernel 1: L2-normalize rows -> bf16; zero out[0] ----------
__global__ __launch_bounds__(256) void k_normalize(const float* __restrict__ x,
                                                   unsigned short* __restrict__ fb,
                                                   float* __restrict__ out) {
  const int row = blockIdx.x * 4 + (threadIdx.x >> 6);
  const int lane = threadIdx.x & 63;
  const float* rp = x + (size_t)row * D + lane * 8;
  float4 v0 = *reinterpret_cast<const float4*>(rp);
  float4 v1 = *reinterpret_cast<const float4*>(rp + 4);
  float s = v0.x*v0.x + v0.y*v0.y + v0.z*v0.z + v0.w*v0.w
          + v1.x*v1.x + v1.y*v1.y + v1.z*v1.z + v1.w*v1.w;
  #pragma unroll
  for (int m = 1; m < 64; m <<= 1) s += __shfl_xor(s, m);
  float inv = 1.0f / fmaxf(sqrtf(s), 1e-12f);
  u16x8 o;
  o[0] = f2bf(v0.x*inv); o[1] = f2bf(v0.y*inv); o[2] = f2bf(v0.z*inv); o[3] = f2bf(v0.w*inv);
  o[4] = f2bf(v1.x*inv); o[5] = f2bf(v1.y*inv); o[6] = f2bf(v1.z*inv); o[7] = f2bf(v1.w*inv);
  *reinterpret_cast<u16x8*>(fb + (size_t)row * D + lane * 8) = o;
  if (blockIdx.x == 0 && threadIdx.x == 0) out[0] = 0.0f;
}

// ---------------- kernel 2: fused GEMM + exp-rowsum + masked-sum -------------
// R7 base (validated 57us) + two in-structure changes:
//  (a) hoisted per-thread staging pointers pA[4]/pB[4] (kills per-tile addr VALU)
//  (b) 1.5-buffer: B double-buffered, stage B(kt+1) issued BEFORE compute(kt)
//      so its HBM/L2 latency hides under the MFMA work; A single-buffered,
//      staged between the two barriers (latency exposed, as in R7).
//      Epilogue reduce arrays overlay Bs0 (last read at kt=6) -> LDS 50.2KB,
//      3 blocks/CU preserved (the R8 dbuf failure was lost residency, not dbuf).
#define GLOAD_LDS16(g, l) __builtin_amdgcn_global_load_lds( \
    (const __attribute__((address_space(1))) unsigned int*)(g), \
    (__attribute__((address_space(3))) unsigned int*)(l), 16, 0, 0)

__global__ __launch_bounds__(256, 3) void k_gemm(
    const unsigned short* __restrict__ fb, const int* __restrict__ labels,
    float* __restrict__ part_e, float* __restrict__ part_p) {
  __shared__ __align__(16) short As[BM * BK];    // 16 KB
  __shared__ __align__(16) short Bs0[BN * BK];   // 16 KB (epilogue overlay: 1024 floats)
  __shared__ __align__(16) short Bs1[BN * BK];   // 16 KB
  __shared__ int labR[BM];
  __shared__ int labC[BN];

  const int tid = threadIdx.x;
  const int lane = tid & 63;
  const int w = tid >> 6;
  const int wr = w >> 1, wc = w & 1;
  const int l15 = lane & 15;

  // XCD-chunked bijective swizzle (NTRI % 8 == 0)
  const int b0 = blockIdx.x;
  const int t = (b0 & 7) * (NTRI / 8) + (b0 >> 3);

  // triangle index -> (bx, by), by <= bx
  int bx = (int)((sqrtf(8.0f * (float)t + 1.0f) - 1.0f) * 0.5f);
  while ((bx + 1) * (bx + 2) / 2 <= t) ++bx;
  while (bx * (bx + 1) / 2 > t) --bx;
  const int by = t - bx * (bx + 1) / 2;
  const bool offdiag = (bx != by);

  const int rowA0 = by * BM, rowB0 = bx * BN;

  if (tid < BM) labR[tid] = labels[rowA0 + tid];
  else          labC[tid - BM] = labels[rowB0 + (tid - BM)];

  f32x4 acc[4][4] = {};

  // ---- hoisted per-thread staging pointers (swizzled source, R7 layout) ----
  const int r0 = tid >> 3;                        // 0..31
  const int sw = (((tid & 7) ^ (r0 & 7)) << 3);   // swizzled k-slot (r&7 == r0&7 for all it)
  const unsigned short* pA[4];
  const unsigned short* pB[4];
  #pragma unroll
  for (int it = 0; it < 4; ++it) {
    pA[it] = fb + (size_t)(rowA0 + it * 32 + r0) * D + sw;
    pB[it] = fb + (size_t)(rowB0 + it * 32 + r0) * D + sw;
  }

#define STAGE_A(kt) do { \
    _Pragma("unroll") \
    for (int it = 0; it < 4; ++it) \
      GLOAD_LDS16(pA[it] + (kt) * BK, (char*)As + it * 4096 + w * 1024); \
  } while (0)
#define STAGE_B(kt, BD) do { \
    _Pragma("unroll") \
    for (int it = 0; it < 4; ++it) \
      GLOAD_LDS16(pB[it] + (kt) * BK, (char*)(BD) + it * 4096 + w * 1024); \
  } while (0)

#define COMPUTE_TILE(BS) do { \
    _Pragma("unroll") \
    for (int kk = 0; kk < BK; kk += 32) { \
      bf16x8 af[4], bg[4]; \
      int kb = (kk + ((lane >> 4) << 3)) * 2; \
      _Pragma("unroll") \
      for (int m = 0; m < 4; ++m) { \
        int ar = wr * 64 + m * 16 + l15; \
        af[m] = *reinterpret_cast<const bf16x8*>( \
            (const char*)As + ar * 128 + (kb ^ ((ar & 7) << 4))); \
      } \
      _Pragma("unroll") \
      for (int n = 0; n < 4; ++n) { \
        int br = wc * 64 + n * 16 + l15; \
        bg[n] = *reinterpret_cast<const bf16x8*>( \
            (const char*)(BS) + br * 128 + (kb ^ ((br & 7) << 4))); \
      } \
      _Pragma("unroll") \
      for (int m = 0; m < 4; ++m) \
        _Pragma("unroll") \
        for (int n = 0; n < 4; ++n) \
          acc[m][n] = __builtin_amdgcn_mfma_f32_16x16x32_bf16(af[m], bg[n], acc[m][n], 0, 0, 0); \
    } } while (0)

  // prologue: tile 0 (A and B) staged; drain
  STAGE_A(0);
  STAGE_B(0, Bs0);
  __syncthreads();

  // per iter: B(kt+1) in flight DURING compute(kt); A(kt+1) between barriers.
  // barrier1 drains B-next (+ own ds_reads, all waves done reading As);
  // barrier2 drains A-next. kt even reads Bs0, odd reads Bs1.
  #pragma unroll
  for (int kt = 0; kt < NKT; ++kt) {
    if (kt + 1 < NKT) {
      if ((kt & 1) == 0) STAGE_B(kt + 1, Bs1);
      else               STAGE_B(kt + 1, Bs0);
    }
    if ((kt & 1) == 0) COMPUTE_TILE(Bs0);
    else               COMPUTE_TILE(Bs1);
    __syncthreads();
    if (kt + 1 < NKT) STAGE_A(kt + 1);
    __syncthreads();
  }

  // ---- fused epilogue; reduce arrays overlay Bs0 (last read kt=6) ----
  float* fo = (float*)Bs0;
  // [0]e_row[2][128] [256]p_row[2][128] [512]e_col[2][128] [768]p_col[2][128]

  float ecol[4] = {};
  float pcol[4] = {};
  int lc[4];
  #pragma unroll
  for (int n = 0; n < 4; ++n)
    lc[n] = labC[wc * 64 + n * 16 + l15];

  #pragma unroll
  for (int m = 0; m < 4; ++m)
    #pragma unroll
    for (int r = 0; r < 4; ++r) {
      int rowl = wr * 64 + m * 16 + ((lane >> 4) << 2) + r;
      int lrv = labR[rowl];
      float e = 0.0f, p = 0.0f;
      #pragma unroll
      for (int n = 0; n < 4; ++n) {
        float s = acc[m][n][r] * INVT;
        float ex = __expf(s);
        float pm = (lrv == lc[n]) ? s : 0.0f;
        e += ex; p += pm;
        ecol[n] += ex; pcol[n] += pm;
      }
      #pragma unroll
      for (int msk = 1; msk < 16; msk <<= 1) {
        e += __shfl_xor(e, msk);
        p += __shfl_xor(p, msk);
      }
      if (l15 == 0) {
        fo[wc * 128 + rowl] = e;
        fo[256 + wc * 128 + rowl] = p;
      }
    }

  // col-partials: reduce across the 4 row-groups (lane>>4)
  if (offdiag) {
    #pragma unroll
    for (int n = 0; n < 4; ++n) {
      float e = ecol[n], p = pcol[n];
      e += __shfl_xor(e, 16); e += __shfl_xor(e, 32);
      p += __shfl_xor(p, 16); p += __shfl_xor(p, 32);
      if (lane < 16) {
        int c = wc * 64 + n * 16 + l15;
        fo[512 + wr * 128 + c] = e;
        fo[768 + wr * 128 + c] = p;
      }
    }
  }
  __syncthreads();

  if (tid < BM) {
    float e = fo[tid] + fo[128 + tid];
    float p = fo[256 + tid] + fo[384 + tid];
    size_t off = (size_t)bx * N + rowA0 + tid;
    part_e[off] = e;
    part_p[off] = p;
  } else if (offdiag) {
    int c = tid - BM;
    float e = fo[512 + c] + fo[640 + c];
    float p = fo[768 + c] + fo[896 + c];
    size_t off = (size_t)by * N + rowB0 + c;
    part_e[off] = e;
    part_p[off] = p;
  }
}

// ---------------- kernel 3: per-row loss + atomic mean ----------------------
__global__ __launch_bounds__(256) void k_final(
    const float* __restrict__ part_e, const float* __restrict__ part_p,
    const int* __restrict__ labels, float* __restrict__ out) {
  __shared__ int h[128];
  const int tid = threadIdx.x;
  if (tid < 128) h[tid] = 0;
  __syncthreads();
  for (int j = tid; j < N; j += 256) atomicAdd(&h[labels[j]], 1);

  const int i = blockIdx.x * 256 + tid;
  float e = 0.0f, p = 0.0f;
  #pragma unroll 8
  for (int cb = 0; cb < NCB; ++cb) {
    e += part_e[(size_t)cb * N + i];
    p += part_p[(size_t)cb * N + i];
  }
  __syncthreads();
  float cnt = (float)h[labels[i]];
  float li = logf(e) - p / cnt;
  #pragma unroll
  for (int m = 1; m < 64; m <<= 1) li += __shfl_xor(li, m);
  __shared__ float red[4];
  if ((tid & 63) == 0) red[tid >> 6] = li;
  __syncthreads();
  if (tid == 0)
    atomicAdd(out, (red[0] + red[1] + red[2] + red[3]) * (1.0f / (float)N));
}

extern "C" void kernel_launch(void* const* d_in, const int* in_sizes, int n_in,
                              void* d_out, int out_size, void* d_ws, size_t ws_size,
                              hipStream_t stream) {
  const float* x = (const float*)d_in[0];
  const int* labels = (const int*)d_in[1];
  float* out = (float*)d_out;
  char* ws = (char*)d_ws;

  unsigned short* fb = (unsigned short*)ws;                      // 8 MB bf16 normalized
  float* part_e = (float*)(ws + (size_t)8  * 1024 * 1024);       // 2 MB (64 x 8192)
  float* part_p = (float*)(ws + (size_t)10 * 1024 * 1024);       // 2 MB

  k_normalize<<<N / 4, 256, 0, stream>>>(x, fb, out);
  k_gemm<<<NTRI, 256, 0, stream>>>(fb, labels, part_e, part_p);
  k_final<<<N / 256, 256, 0, stream>>>(part_e, part_p, labels, out);
}

// Round 14
// 68.002 us; speedup vs baseline: 1.4274x; 1.1912x over previous
//
#include <hip/hip_runtime.h>
#include <hip/hip_bf16.h>

#define N 8192
#define D 512
#define BM 128
#define BN 128
#define NCB (N / BN)   // 64 column blocks
#define NCH 4          // K-chunks of 128 i8 (= 128 B per row per chunk)
#define NTRI (NCB * (NCB + 1) / 2)  // 2080 upper-triangle blocks (2080 % 8 == 0)
#define INVT 14.285714285714286f

typedef __attribute__((ext_vector_type(4))) int i32x4;

// ---------------- kernel 1: L2-normalize + per-row absmax int8 quantize ------
// (R9-validated numerics: absmax 0.0.) Also zeroes out[0].
__global__ __launch_bounds__(256) void k_normalize(const float* __restrict__ x,
                                                   signed char* __restrict__ q8,
                                                   float* __restrict__ srow,
                                                   float* __restrict__ out) {
  const int row = blockIdx.x * 4 + (threadIdx.x >> 6);
  const int lane = threadIdx.x & 63;
  const float* rp = x + (size_t)row * D + lane * 8;
  float4 v0 = *reinterpret_cast<const float4*>(rp);
  float4 v1 = *reinterpret_cast<const float4*>(rp + 4);
  float s = v0.x*v0.x + v0.y*v0.y + v0.z*v0.z + v0.w*v0.w
          + v1.x*v1.x + v1.y*v1.y + v1.z*v1.z + v1.w*v1.w;
  #pragma unroll
  for (int m = 1; m < 64; m <<= 1) s += __shfl_xor(s, m);
  float inv = 1.0f / fmaxf(sqrtf(s), 1e-12f);
  float f[8];
  f[0]=v0.x*inv; f[1]=v0.y*inv; f[2]=v0.z*inv; f[3]=v0.w*inv;
  f[4]=v1.x*inv; f[5]=v1.y*inv; f[6]=v1.z*inv; f[7]=v1.w*inv;
  float mx = 0.0f;
  #pragma unroll
  for (int j = 0; j < 8; ++j) mx = fmaxf(mx, fabsf(f[j]));
  #pragma unroll
  for (int m = 1; m < 64; m <<= 1) mx = fmaxf(mx, __shfl_xor(mx, m));
  mx = fmaxf(mx, 1e-20f);
  const float qm = 127.0f / mx;
  unsigned int b[8];
  #pragma unroll
  for (int j = 0; j < 8; ++j) b[j] = (unsigned int)(__float2int_rn(f[j] * qm)) & 255u;
  uint2 pk;
  pk.x = b[0] | (b[1] << 8) | (b[2] << 16) | (b[3] << 24);
  pk.y = b[4] | (b[5] << 8) | (b[6] << 16) | (b[7] << 24);
  *reinterpret_cast<uint2*>(q8 + (size_t)row * D + lane * 8) = pk;
  if (lane == 0) srow[row] = mx * (1.0f / 127.0f);
  if (blockIdx.x == 0 && threadIdx.x == 0) out[0] = 0.0f;
}

// ---------------- kernel 2: fused int8 GEMM + exp-rowsum + masked-sum --------
// R9's K-loop (i8 K=128 chunks, correctness-validated) + R11's LEAN epilogue
// (e/p only — R10 proved the 3-accumulator epilogue spills; count lives in
// k_final's hist). Dequant scales are read from LDS inside the epilogue loops,
// NOT cached in registers, to stay below the (256,3) register cliff.
#define GLOAD_LDS16(g, l) __builtin_amdgcn_global_load_lds( \
    (const __attribute__((address_space(1))) unsigned int*)(g), \
    (__attribute__((address_space(3))) unsigned int*)(l), 16, 0, 0)

__global__ __launch_bounds__(256, 3) void k_gemm(
    const signed char* __restrict__ q8, const float* __restrict__ srow,
    const int* __restrict__ labels,
    float* __restrict__ part_e, float* __restrict__ part_p) {
  __shared__ __align__(16) char As[BM * 128];   // 16 KB (one K-chunk of A rows)
  __shared__ __align__(16) char Bs[BN * 128];   // 16 KB
  __shared__ float e_part[2][BM];
  __shared__ float p_part[2][BM];
  __shared__ float e_cpart[2][BN];
  __shared__ float p_cpart[2][BN];
  __shared__ int labR[BM];
  __shared__ int labC[BN];
  __shared__ float saR[BM];
  __shared__ float sbC[BN];

  const int tid = threadIdx.x;
  const int lane = tid & 63;
  const int w = tid >> 6;
  const int wr = w >> 1, wc = w & 1;
  const int l15 = lane & 15;

  // XCD-chunked bijective swizzle (NTRI % 8 == 0)
  const int b0 = blockIdx.x;
  const int t = (b0 & 7) * (NTRI / 8) + (b0 >> 3);

  int bx = (int)((sqrtf(8.0f * (float)t + 1.0f) - 1.0f) * 0.5f);
  while ((bx + 1) * (bx + 2) / 2 <= t) ++bx;
  while (bx * (bx + 1) / 2 > t) --bx;
  const int by = t - bx * (bx + 1) / 2;
  const bool offdiag = (bx != by);

  const int rowA0 = by * BM, rowB0 = bx * BN;

  if (tid < BM) {
    labR[tid] = labels[rowA0 + tid];
    saR[tid] = srow[rowA0 + tid];
  } else {
    labC[tid - BM] = labels[rowB0 + (tid - BM)];
    sbC[tid - BM] = srow[rowB0 + (tid - BM)];
  }

  i32x4 acc[4][4] = {};
  const int sslot = tid & 7;

  for (int c = 0; c < NCH; ++c) {
    if (c) __syncthreads();
    const int kbase = c * 128;         // byte offset within a 512B row
    #pragma unroll
    for (int it = 0; it < 4; ++it) {
      int r = (it * 256 + tid) >> 3;
      int kcol = ((sslot ^ (r & 7)) << 4) + kbase;   // pre-swizzled 16B slot
      GLOAD_LDS16(q8 + (size_t)(rowA0 + r) * D + kcol,
                  As + it * 4096 + w * 1024);
    }
    #pragma unroll
    for (int it = 0; it < 4; ++it) {
      int r = (it * 256 + tid) >> 3;
      int kcol = ((sslot ^ (r & 7)) << 4) + kbase;
      GLOAD_LDS16(q8 + (size_t)(rowB0 + r) * D + kcol,
                  Bs + it * 4096 + w * 1024);
    }
    __syncthreads();

    #pragma unroll
    for (int ks = 0; ks < 2; ++ks) {   // two K=64 halves of the 128B chunk
      i32x4 af[4], bg[4];
      #pragma unroll
      for (int m = 0; m < 4; ++m) {
        int ar = wr * 64 + m * 16 + l15;
        int boff = ((ks * 4 + (lane >> 4)) ^ (ar & 7)) << 4;
        af[m] = *reinterpret_cast<const i32x4*>(As + ar * 128 + boff);
      }
      #pragma unroll
      for (int n = 0; n < 4; ++n) {
        int br = wc * 64 + n * 16 + l15;
        int boff = ((ks * 4 + (lane >> 4)) ^ (br & 7)) << 4;
        bg[n] = *reinterpret_cast<const i32x4*>(Bs + br * 128 + boff);
      }
      #pragma unroll
      for (int m = 0; m < 4; ++m)
        #pragma unroll
        for (int n = 0; n < 4; ++n)
          acc[m][n] = __builtin_amdgcn_mfma_i32_16x16x64_i8(af[m], bg[n], acc[m][n], 0, 0, 0);
    }
  }

  // ---- fused LEAN epilogue (e/p only; scales read from LDS per use) ----
  __syncthreads();                     // waves done with As/Bs ds_reads
  float ecol[4] = {};
  float pcol[4] = {};
  int lc[4];
  #pragma unroll
  for (int n = 0; n < 4; ++n)
    lc[n] = labC[wc * 64 + n * 16 + l15];

  #pragma unroll
  for (int m = 0; m < 4; ++m)
    #pragma unroll
    for (int r = 0; r < 4; ++r) {
      int rowl = wr * 64 + m * 16 + ((lane >> 4) << 2) + r;
      int lrv = labR[rowl];
      float pre = saR[rowl] * INVT;
      float e = 0.0f, p = 0.0f;
      #pragma unroll
      for (int n = 0; n < 4; ++n) {
        float s = (float)acc[m][n][r] * pre * sbC[wc * 64 + n * 16 + l15];
        float ex = __expf(s);
        float pm = (lrv == lc[n]) ? s : 0.0f;
        e += ex; p += pm;
        ecol[n] += ex; pcol[n] += pm;
      }
      #pragma unroll
      for (int msk = 1; msk < 16; msk <<= 1) {
        e += __shfl_xor(e, msk);
        p += __shfl_xor(p, msk);
      }
      if (l15 == 0) {
        e_part[wc][rowl] = e;
        p_part[wc][rowl] = p;
      }
    }

  if (offdiag) {
    #pragma unroll
    for (int n = 0; n < 4; ++n) {
      float e = ecol[n], p = pcol[n];
      e += __shfl_xor(e, 16); e += __shfl_xor(e, 32);
      p += __shfl_xor(p, 16); p += __shfl_xor(p, 32);
      if (lane < 16) {
        int cidx = wc * 64 + n * 16 + l15;
        e_cpart[wr][cidx] = e;
        p_cpart[wr][cidx] = p;
      }
    }
  }
  __syncthreads();

  if (tid < BM) {
    float e = e_part[0][tid] + e_part[1][tid];
    float p = p_part[0][tid] + p_part[1][tid];
    size_t off = (size_t)bx * N + rowA0 + tid;
    part_e[off] = e;
    part_p[off] = p;
  } else if (offdiag) {
    int cidx = tid - BM;
    float e = e_cpart[0][cidx] + e_cpart[1][cidx];
    float p = p_cpart[0][cidx] + p_cpart[1][cidx];
    size_t off = (size_t)by * N + rowB0 + cidx;
    part_e[off] = e;
    part_p[off] = p;
  }
}

// ---------------- kernel 3: per-row loss + atomic mean ----------------------
__global__ __launch_bounds__(256) void k_final(
    const float* __restrict__ part_e, const float* __restrict__ part_p,
    const int* __restrict__ labels, float* __restrict__ out) {
  __shared__ int h[128];
  const int tid = threadIdx.x;
  if (tid < 128) h[tid] = 0;
  __syncthreads();
  for (int j = tid; j < N; j += 256) atomicAdd(&h[labels[j]], 1);

  const int i = blockIdx.x * 256 + tid;
  float e = 0.0f, p = 0.0f;
  #pragma unroll 8
  for (int cb = 0; cb < NCB; ++cb) {
    e += part_e[(size_t)cb * N + i];
    p += part_p[(size_t)cb * N + i];
  }
  __syncthreads();
  float cnt = (float)h[labels[i]];
  float li = logf(e) - p / cnt;
  #pragma unroll
  for (int m = 1; m < 64; m <<= 1) li += __shfl_xor(li, m);
  __shared__ float red[4];
  if ((tid & 63) == 0) red[tid >> 6] = li;
  __syncthreads();
  if (tid == 0)
    atomicAdd(out, (red[0] + red[1] + red[2] + red[3]) * (1.0f / (float)N));
}

extern "C" void kernel_launch(void* const* d_in, const int* in_sizes, int n_in,
                              void* d_out, int out_size, void* d_ws, size_t ws_size,
                              hipStream_t stream) {
  const float* x = (const float*)d_in[0];
  const int* labels = (const int*)d_in[1];
  float* out = (float*)d_out;
  char* ws = (char*)d_ws;

  signed char* q8 = (signed char*)ws;                        // 4 MB int8 rows
  float* srow     = (float*)(ws + (size_t)4 * 1024 * 1024);  // 32 KB scales
  float* part_e   = (float*)(ws + (size_t)5 * 1024 * 1024);  // 2 MB (64 x 8192)
  float* part_p   = (float*)(ws + (size_t)7 * 1024 * 1024);  // 2 MB

  k_normalize<<<N / 4, 256, 0, stream>>>(x, q8, srow, out);
  k_gemm<<<NTRI, 256, 0, stream>>>(q8, srow, labels, part_e, part_p);
  k_final<<<N / 256, 256, 0, stream>>>(part_e, part_p, labels, out);
}

// Round 15
// 66.894 us; speedup vs baseline: 1.4511x; 1.0166x over previous
//
#include <hip/hip_runtime.h>
#include <hip/hip_bf16.h>

#define N 8192
#define D 512
#define BM 128
#define BN 128
#define NCB (N / BN)   // 64 column blocks
#define NCH 4          // K-chunks of 128 i8 (= 128 B per row per chunk)
#define NTRI (NCB * (NCB + 1) / 2)  // 2080 upper-triangle blocks (2080 % 8 == 0)
#define INVT 14.285714285714286f

typedef __attribute__((ext_vector_type(4))) int i32x4;

// ---------------- kernel 1: L2-normalize + per-row absmax int8 quantize ------
__global__ __launch_bounds__(256) void k_normalize(const float* __restrict__ x,
                                                   signed char* __restrict__ q8,
                                                   float* __restrict__ srow,
                                                   float* __restrict__ out) {
  const int row = blockIdx.x * 4 + (threadIdx.x >> 6);
  const int lane = threadIdx.x & 63;
  const float* rp = x + (size_t)row * D + lane * 8;
  float4 v0 = *reinterpret_cast<const float4*>(rp);
  float4 v1 = *reinterpret_cast<const float4*>(rp + 4);
  float s = v0.x*v0.x + v0.y*v0.y + v0.z*v0.z + v0.w*v0.w
          + v1.x*v1.x + v1.y*v1.y + v1.z*v1.z + v1.w*v1.w;
  #pragma unroll
  for (int m = 1; m < 64; m <<= 1) s += __shfl_xor(s, m);
  float inv = 1.0f / fmaxf(sqrtf(s), 1e-12f);
  float f[8];
  f[0]=v0.x*inv; f[1]=v0.y*inv; f[2]=v0.z*inv; f[3]=v0.w*inv;
  f[4]=v1.x*inv; f[5]=v1.y*inv; f[6]=v1.z*inv; f[7]=v1.w*inv;
  float mx = 0.0f;
  #pragma unroll
  for (int j = 0; j < 8; ++j) mx = fmaxf(mx, fabsf(f[j]));
  #pragma unroll
  for (int m = 1; m < 64; m <<= 1) mx = fmaxf(mx, __shfl_xor(mx, m));
  mx = fmaxf(mx, 1e-20f);
  const float qm = 127.0f / mx;
  unsigned int b[8];
  #pragma unroll
  for (int j = 0; j < 8; ++j) b[j] = (unsigned int)(__float2int_rn(f[j] * qm)) & 255u;
  uint2 pk;
  pk.x = b[0] | (b[1] << 8) | (b[2] << 16) | (b[3] << 24);
  pk.y = b[4] | (b[5] << 8) | (b[6] << 16) | (b[7] << 24);
  *reinterpret_cast<uint2*>(q8 + (size_t)row * D + lane * 8) = pk;
  if (lane == 0) srow[row] = mx * (1.0f / 127.0f);
  if (blockIdx.x == 0 && threadIdx.x == 0) out[0] = 0.0f;
}

// ---------------- kernel 2: fused int8 GEMM + exp-rowsum + masked-sum --------
// R14 kernel (validated 42.2us, no spill) + two reg-budget spends from the 26
// free arch regs (80+64=144 of 170 @ 3 blocks/CU):
//  (a) sc[4] dequant scales cached in regs (removes 64 LDS reads/thread)
//  (b) hoisted staging pointers pA[4]/pB[4] (kills per-chunk addr VALU)
#define GLOAD_LDS16(g, l) __builtin_amdgcn_global_load_lds( \
    (const __attribute__((address_space(1))) unsigned int*)(g), \
    (__attribute__((address_space(3))) unsigned int*)(l), 16, 0, 0)

__global__ __launch_bounds__(256, 3) void k_gemm(
    const signed char* __restrict__ q8, const float* __restrict__ srow,
    const int* __restrict__ labels,
    float* __restrict__ part_e, float* __restrict__ part_p) {
  __shared__ __align__(16) char As[BM * 128];   // 16 KB (one K-chunk of A rows)
  __shared__ __align__(16) char Bs[BN * 128];   // 16 KB
  __shared__ float e_part[2][BM];
  __shared__ float p_part[2][BM];
  __shared__ float e_cpart[2][BN];
  __shared__ float p_cpart[2][BN];
  __shared__ int labR[BM];
  __shared__ int labC[BN];
  __shared__ float saR[BM];
  __shared__ float sbC[BN];

  const int tid = threadIdx.x;
  const int lane = tid & 63;
  const int w = tid >> 6;
  const int wr = w >> 1, wc = w & 1;
  const int l15 = lane & 15;

  // XCD-chunked bijective swizzle (NTRI % 8 == 0)
  const int b0 = blockIdx.x;
  const int t = (b0 & 7) * (NTRI / 8) + (b0 >> 3);

  int bx = (int)((sqrtf(8.0f * (float)t + 1.0f) - 1.0f) * 0.5f);
  while ((bx + 1) * (bx + 2) / 2 <= t) ++bx;
  while (bx * (bx + 1) / 2 > t) --bx;
  const int by = t - bx * (bx + 1) / 2;
  const bool offdiag = (bx != by);

  const int rowA0 = by * BM, rowB0 = bx * BN;

  if (tid < BM) {
    labR[tid] = labels[rowA0 + tid];
    saR[tid] = srow[rowA0 + tid];
  } else {
    labC[tid - BM] = labels[rowB0 + (tid - BM)];
    sbC[tid - BM] = srow[rowB0 + (tid - BM)];
  }

  i32x4 acc[4][4] = {};

  // hoisted per-thread staging pointers (pre-swizzled 16B source slot)
  const int r0 = tid >> 3;                         // 0..31
  const int sw = (((tid & 7) ^ (r0 & 7)) << 4);    // r&7 == r0&7 for all it
  const signed char* pA[4];
  const signed char* pB[4];
  #pragma unroll
  for (int it = 0; it < 4; ++it) {
    pA[it] = q8 + (size_t)(rowA0 + it * 32 + r0) * D + sw;
    pB[it] = q8 + (size_t)(rowB0 + it * 32 + r0) * D + sw;
  }

  for (int c = 0; c < NCH; ++c) {
    if (c) __syncthreads();
    const int kbase = c * 128;         // byte offset within a 512B row
    #pragma unroll
    for (int it = 0; it < 4; ++it)
      GLOAD_LDS16(pA[it] + kbase, As + it * 4096 + w * 1024);
    #pragma unroll
    for (int it = 0; it < 4; ++it)
      GLOAD_LDS16(pB[it] + kbase, Bs + it * 4096 + w * 1024);
    __syncthreads();

    #pragma unroll
    for (int ks = 0; ks < 2; ++ks) {   // two K=64 halves of the 128B chunk
      i32x4 af[4], bg[4];
      #pragma unroll
      for (int m = 0; m < 4; ++m) {
        int ar = wr * 64 + m * 16 + l15;
        int boff = ((ks * 4 + (lane >> 4)) ^ (ar & 7)) << 4;
        af[m] = *reinterpret_cast<const i32x4*>(As + ar * 128 + boff);
      }
      #pragma unroll
      for (int n = 0; n < 4; ++n) {
        int br = wc * 64 + n * 16 + l15;
        int boff = ((ks * 4 + (lane >> 4)) ^ (br & 7)) << 4;
        bg[n] = *reinterpret_cast<const i32x4*>(Bs + br * 128 + boff);
      }
      #pragma unroll
      for (int m = 0; m < 4; ++m)
        #pragma unroll
        for (int n = 0; n < 4; ++n)
          acc[m][n] = __builtin_amdgcn_mfma_i32_16x16x64_i8(af[m], bg[n], acc[m][n], 0, 0, 0);
    }
  }

  // ---- fused LEAN epilogue (e/p only; sc[4] cached in regs) ----
  __syncthreads();                     // waves done with As/Bs ds_reads
  float ecol[4] = {};
  float pcol[4] = {};
  int lc[4];
  float sc[4];
  #pragma unroll
  for (int n = 0; n < 4; ++n) {
    int cidx = wc * 64 + n * 16 + l15;
    lc[n] = labC[cidx];
    sc[n] = sbC[cidx];
  }

  #pragma unroll
  for (int m = 0; m < 4; ++m)
    #pragma unroll
    for (int r = 0; r < 4; ++r) {
      int rowl = wr * 64 + m * 16 + ((lane >> 4) << 2) + r;
      int lrv = labR[rowl];
      float pre = saR[rowl] * INVT;
      float e = 0.0f, p = 0.0f;
      #pragma unroll
      for (int n = 0; n < 4; ++n) {
        float s = (float)acc[m][n][r] * pre * sc[n];
        float ex = __expf(s);
        float pm = (lrv == lc[n]) ? s : 0.0f;
        e += ex; p += pm;
        ecol[n] += ex; pcol[n] += pm;
      }
      #pragma unroll
      for (int msk = 1; msk < 16; msk <<= 1) {
        e += __shfl_xor(e, msk);
        p += __shfl_xor(p, msk);
      }
      if (l15 == 0) {
        e_part[wc][rowl] = e;
        p_part[wc][rowl] = p;
      }
    }

  if (offdiag) {
    #pragma unroll
    for (int n = 0; n < 4; ++n) {
      float e = ecol[n], p = pcol[n];
      e += __shfl_xor(e, 16); e += __shfl_xor(e, 32);
      p += __shfl_xor(p, 16); p += __shfl_xor(p, 32);
      if (lane < 16) {
        int cidx = wc * 64 + n * 16 + l15;
        e_cpart[wr][cidx] = e;
        p_cpart[wr][cidx] = p;
      }
    }
  }
  __syncthreads();

  if (tid < BM) {
    float e = e_part[0][tid] + e_part[1][tid];
    float p = p_part[0][tid] + p_part[1][tid];
    size_t off = (size_t)bx * N + rowA0 + tid;
    part_e[off] = e;
    part_p[off] = p;
  } else if (offdiag) {
    int cidx = tid - BM;
    float e = e_cpart[0][cidx] + e_cpart[1][cidx];
    float p = p_cpart[0][cidx] + p_cpart[1][cidx];
    size_t off = (size_t)by * N + rowB0 + cidx;
    part_e[off] = e;
    part_p[off] = p;
  }
}

// ---------------- kernel 3: per-row loss + atomic mean ----------------------
__global__ __launch_bounds__(256) void k_final(
    const float* __restrict__ part_e, const float* __restrict__ part_p,
    const int* __restrict__ labels, float* __restrict__ out) {
  __shared__ int h[128];
  const int tid = threadIdx.x;
  if (tid < 128) h[tid] = 0;
  __syncthreads();
  for (int j = tid; j < N; j += 256) atomicAdd(&h[labels[j]], 1);

  const int i = blockIdx.x * 256 + tid;
  float e = 0.0f, p = 0.0f;
  #pragma unroll 8
  for (int cb = 0; cb < NCB; ++cb) {
    e += part_e[(size_t)cb * N + i];
    p += part_p[(size_t)cb * N + i];
  }
  __syncthreads();
  float cnt = (float)h[labels[i]];
  float li = logf(e) - p / cnt;
  #pragma unroll
  for (int m = 1; m < 64; m <<= 1) li += __shfl_xor(li, m);
  __shared__ float red[4];
  if ((tid & 63) == 0) red[tid >> 6] = li;
  __syncthreads();
  if (tid == 0)
    atomicAdd(out, (red[0] + red[1] + red[2] + red[3]) * (1.0f / (float)N));
}

extern "C" void kernel_launch(void* const* d_in, const int* in_sizes, int n_in,
                              void* d_out, int out_size, void* d_ws, size_t ws_size,
                              hipStream_t stream) {
  const float* x = (const float*)d_in[0];
  const int* labels = (const int*)d_in[1];
  float* out = (float*)d_out;
  char* ws = (char*)d_ws;

  signed char* q8 = (signed char*)ws;                        // 4 MB int8 rows
  float* srow     = (float*)(ws + (size_t)4 * 1024 * 1024);  // 32 KB scales
  float* part_e   = (float*)(ws + (size_t)5 * 1024 * 1024);  // 2 MB (64 x 8192)
  float* part_p   = (float*)(ws + (size_t)7 * 1024 * 1024);  // 2 MB

  k_normalize<<<N / 4, 256, 0, stream>>>(x, q8, srow, out);
  k_gemm<<<NTRI, 256, 0, stream>>>(q8, srow, labels, part_e, part_p);
  k_final<<<N / 256, 256, 0, stream>>>(part_e, part_p, labels, out);
}